// Round 1
// baseline (85.266 us; speedup 1.0000x reference)
//
#include <hip/hip_runtime.h>
#include <hip/hip_bf16.h>

// Problem: VectorQuantizer, B=8 C=16 H=64 W=64, D=1, N=512.
// E = 524288 input/output elements + 2 scalar losses.
//
// Reference semantics (including the deliberate reshape bug):
//   argmin_flat[i] over n of (x_flat[i] - weight[n])^2, i in BCHW order
//   quantized[b,c,h,w] = weight[ argmin_flat[ ((b*H+h)*W+w)*C + c ] ]
//   both losses = mean over BCHW of (x - quantized)^2
//   quantized_st forward value == quantized.

#define E_TOTAL 524288
#define NCODE   512
#define BLOCK   256
#define NBLOCKS (E_TOTAL / BLOCK)   // 2048

__global__ __launch_bounds__(BLOCK) void vq_main_kernel(
    const float* __restrict__ x, const float* __restrict__ wt,
    float* __restrict__ out, double* __restrict__ partial) {
  __shared__ float lw[NCODE];
  __shared__ double lsum[BLOCK / 64];

  const int t = threadIdx.x;
  // Stage codebook into LDS (512 floats = 2 KB), 2 per thread.
  for (int k = t; k < NCODE; k += BLOCK) lw[k] = wt[k];
  __syncthreads();

  const int o = blockIdx.x * BLOCK + t;  // output index, BCHW flat
  // Decode o -> (b,c,h,w): W=64 (6b), H=64 (6b), C=16 (4b), B=8 (3b)
  const int w = o & 63;
  const int h = (o >> 6) & 63;
  const int c = (o >> 12) & 15;
  const int b = o >> 16;
  // Scrambled source index (the reference's reshape-as-[B,H,W,C] bug):
  const int ip = b * 65536 + h * 1024 + w * 16 + c;

  const float xq = x[ip];

  // Packed-key argmin: key = (bits(d2) & ~511) | n; integer min picks
  // smallest d2, ties broken by smallest n (== jnp.argmin first-index).
  unsigned best = 0xFFFFFFFFu;
#pragma unroll 8
  for (int n = 0; n < NCODE; ++n) {
    const float d = xq - lw[n];       // same rounding as reference:
    const float d2 = d * d;           // subtract then square, fp32
    const unsigned key = (__float_as_uint(d2) & 0xFFFFFE00u) | (unsigned)n;
    best = best < key ? best : key;
  }
  const float wq = lw[best & 511u];

  out[o] = wq;

  // Loss term at this output position.
  const float diff = x[o] - wq;
  double ds = (double)diff * (double)diff;

  // Wave(64) shuffle reduction, then per-block partial.
#pragma unroll
  for (int off = 32; off > 0; off >>= 1) ds += __shfl_down(ds, off, 64);
  const int lane = t & 63, wave = t >> 6;
  if (lane == 0) lsum[wave] = ds;
  __syncthreads();
  if (t == 0) {
    double s = 0.0;
#pragma unroll
    for (int i = 0; i < BLOCK / 64; ++i) s += lsum[i];
    partial[blockIdx.x] = s;  // full overwrite: no ws zeroing needed
  }
}

__global__ __launch_bounds__(BLOCK) void vq_reduce_kernel(
    const double* __restrict__ partial, float* __restrict__ out) {
  __shared__ double lsum[BLOCK / 64];
  const int t = threadIdx.x;
  double s = 0.0;
  for (int k = t; k < NBLOCKS; k += BLOCK) s += partial[k];
#pragma unroll
  for (int off = 32; off > 0; off >>= 1) s += __shfl_down(s, off, 64);
  const int lane = t & 63, wave = t >> 6;
  if (lane == 0) lsum[wave] = s;
  __syncthreads();
  if (t == 0) {
    double tot = 0.0;
#pragma unroll
    for (int i = 0; i < BLOCK / 64; ++i) tot += lsum[i];
    const float m = (float)(tot / (double)E_TOTAL);
    out[E_TOTAL] = m;      // q_latent_loss
    out[E_TOTAL + 1] = m;  // e_latent_loss (identical forward value)
  }
}

extern "C" void kernel_launch(void* const* d_in, const int* in_sizes, int n_in,
                              void* d_out, int out_size, void* d_ws, size_t ws_size,
                              hipStream_t stream) {
  const float* x = (const float*)d_in[0];    // 524288 fp32, BCHW flat
  const float* wt = (const float*)d_in[1];   // 512 fp32 (D=1 row)
  float* out = (float*)d_out;                // 524290 fp32
  double* partial = (double*)d_ws;           // 2048 doubles = 16 KB

  vq_main_kernel<<<NBLOCKS, BLOCK, 0, stream>>>(x, wt, out, partial);
  vq_reduce_kernel<<<1, BLOCK, 0, stream>>>(partial, out);
}